// Round 4
// baseline (311.429 us; speedup 1.0000x reference)
//
#include <hip/hip_runtime.h>
#include <stdint.h>

#define H_DIM 1024
#define I_DIM 4096
#define E_NUM 8
#define CAP   1024

typedef __attribute__((ext_vector_type(8))) short bf16x8;
typedef __attribute__((ext_vector_type(4))) float f32x4;

#define AS1 __attribute__((address_space(1)))
#define AS3 __attribute__((address_space(3)))

__device__ __forceinline__ unsigned short f2bf(float f){
  union { float f; uint32_t u; } v; v.f = f;
  uint32_t u = v.u;
  uint32_t r = (u + 0x7FFFu + ((u >> 16) & 1u)) >> 16;
  return (unsigned short)r;
}

// ---------------- zero output ----------------
__global__ void zero_kernel(float4* __restrict__ p, int n4){
  int i = blockIdx.x*blockDim.x + threadIdx.x;
  int stride = gridDim.x*blockDim.x;
  float4 z; z.x=0.f; z.y=0.f; z.z=0.f; z.w=0.f;
  for (; i < n4; i += stride) p[i] = z;
}

// ---------------- router softmax + x -> bf16 (first CAP tokens) ----------------
__global__ __launch_bounds__(256) void router_kernel(
    const float* __restrict__ x, const float* __restrict__ rw_w,
    const float* __restrict__ rb, unsigned short* __restrict__ xb,
    float* __restrict__ rwout)
{
  int c = blockIdx.x;
  int t = threadIdx.x;
  float acc[E_NUM];
  #pragma unroll
  for (int e=0;e<E_NUM;e++) acc[e]=0.f;
  const float* xr = x + (size_t)c*H_DIM;
  for (int h=t; h<H_DIM; h+=256){
    float xv = xr[h];
    xb[(size_t)c*H_DIM + h] = f2bf(xv);
    #pragma unroll
    for (int e=0;e<E_NUM;e++) acc[e] += xv * rw_w[e*H_DIM + h];
  }
  __shared__ float part[256][E_NUM];
  #pragma unroll
  for (int e=0;e<E_NUM;e++) part[t][e]=acc[e];
  __syncthreads();
  for (int s=128; s>0; s>>=1){
    if (t<s){
      #pragma unroll
      for (int e=0;e<E_NUM;e++) part[t][e]+=part[t+s][e];
    }
    __syncthreads();
  }
  if (t==0){
    float l[E_NUM], mx=-1e30f;
    #pragma unroll
    for (int e=0;e<E_NUM;e++){ l[e]=part[0][e]+rb[e]; mx=fmaxf(mx,l[e]); }
    float s=0.f;
    #pragma unroll
    for (int e=0;e<E_NUM;e++){ l[e]=expf(l[e]-mx); s+=l[e]; }
    float inv = 1.f/s;
    #pragma unroll
    for (int e=0;e<E_NUM;e++) rwout[c*E_NUM+e] = l[e]*inv;
  }
}

// ---------------- fp32 -> bf16 transpose (src RxC -> dst CxR) ----------------
__global__ __launch_bounds__(256) void transpose_cvt(
    const float* __restrict__ src, unsigned short* __restrict__ dst,
    int R, int C, long srcZ, long dstZ)
{
  src += (size_t)blockIdx.z * srcZ;
  dst += (size_t)blockIdx.z * dstZ;
  __shared__ float tile[32][33];
  int c0 = blockIdx.x*32, r0 = blockIdx.y*32;
  int tx = threadIdx.x, ty = threadIdx.y;
  #pragma unroll
  for (int j=ty; j<32; j+=8)
    tile[j][tx] = src[(size_t)(r0+j)*C + c0+tx];
  __syncthreads();
  #pragma unroll
  for (int j=ty; j<32; j+=8)
    dst[(size_t)(c0+j)*R + r0+tx] = f2bf(tile[tx][j]);
}

// ---- 256x256 bf16 GEMM, B N-major; depth-3 counted pipeline + 2-phase interleave ----
// 4 LDS buffers x 32KB (A[256x32]+B[256x32]); per half: boundary vmcnt(8)+barrier,
// then 2 phases each {stage 2 gloads, ds_read 1 M-half frags, lgkmcnt(0),
// sched_barrier, setprio(1), 16 MFMA, setprio(0), barrier}.
// MODE 0: relu*rw -> bf16 inter.  MODE 1: atomicAdd fp32.
template<int MODE>
__global__ __launch_bounds__(512, 2) void gemm4b(
    const unsigned short* __restrict__ A, int lda, long aZ,
    const unsigned short* __restrict__ B, int ldb, long bZ,
    int NH, int tilesPerZ,
    const float* __restrict__ rw,
    unsigned short* __restrict__ outInter,
    float* __restrict__ outAdd)
{
  extern __shared__ char smem[];   // 131072 = 4 bufs x (A 16KB | B 16KB)

  // T1: XCD-aware swizzle (gridDim.x % 8 == 0)
  int nwg = gridDim.x;
  int id  = blockIdx.x;
  int swz = (id & 7)*(nwg >> 3) + (id >> 3);
  int z   = swz / tilesPerZ;
  int rr_ = swz - z*tilesPerZ;
  int mt  = rr_ & 3, nt = rr_ >> 2;
  int m0  = mt*256, n0 = nt*256;

  const unsigned short* Ab = A + (size_t)z*aZ + (size_t)m0*lda;
  const unsigned short* Bb = B + (size_t)z*bZ + (size_t)n0*ldb;

  int tid  = threadIdx.x;
  int w    = tid >> 6, l = tid & 63;
  int wr   = w >> 2,  wc = w & 3;       // wave grid 2M x 4N
  int lrow = l & 15,  lq = l >> 4;

  // read-side swizzle: slot = lq ^ ((row>>1)&3); per-lane constant since
  // frag bases are multiples of 16.
  int rsw = (lq ^ ((lrow>>1)&3)) << 4;          // byte offset of 16B slot

  // staging: wave w covers rows [w*32, w*32+32) of both A and B halves.
  int srow  = (l >> 2);
  int sslot = ((l & 3) ^ ((l >> 3) & 3)) * 8;   // inverse-swizzled source slot
  size_t aOff0 = (size_t)(w*32 + srow)      * lda + sslot;
  size_t aOff1 = (size_t)(w*32 + 16 + srow) * lda + sslot;
  size_t bOff0 = (size_t)(w*32 + srow)      * ldb + sslot;
  size_t bOff1 = (size_t)(w*32 + 16 + srow) * ldb + sslot;
  int ldsA0 = (w*32)*64, ldsA1 = (w*32+16)*64;

  auto stageA = [&](int h){
    char* lb = smem + ((h & 3) << 15);
    int kb = h << 5;
    __builtin_amdgcn_global_load_lds((const AS1 void*)(Ab + aOff0 + kb),
        (AS3 void*)(lb + ldsA0), 16, 0, 0);
    __builtin_amdgcn_global_load_lds((const AS1 void*)(Ab + aOff1 + kb),
        (AS3 void*)(lb + ldsA1), 16, 0, 0);
  };
  auto stageB = [&](int h){
    char* lb = smem + ((h & 3) << 15);
    int kb = h << 5;
    __builtin_amdgcn_global_load_lds((const AS1 void*)(Bb + bOff0 + kb),
        (AS3 void*)(lb + 16384 + ldsA0), 16, 0, 0);
    __builtin_amdgcn_global_load_lds((const AS1 void*)(Bb + bOff1 + kb),
        (AS3 void*)(lb + 16384 + ldsA1), 16, 0, 0);
  };

  f32x4 acc[8][4];
  #pragma unroll
  for (int i=0;i<8;i++)
    #pragma unroll
    for (int j=0;j<4;j++)
      acc[i][j] = (f32x4){0.f,0.f,0.f,0.f};

  // prologue: depth-3 prefetch
  stageA(0); stageB(0); stageA(1); stageB(1); stageA(2); stageB(2);

  for (int h = 0; h < NH; ++h){
    // counted boundary wait: 4 outstanding loads per in-flight half
    int pend = NH-1-h; if (pend > 2) pend = 2;
    if (pend == 2)      asm volatile("s_waitcnt vmcnt(8)" ::: "memory");
    else if (pend == 1) asm volatile("s_waitcnt vmcnt(4)" ::: "memory");
    else                asm volatile("s_waitcnt vmcnt(0)" ::: "memory");
    __builtin_amdgcn_s_barrier();

    char* lb = smem + ((h & 3) << 15);
    bool pf = (h+3 < NH);

    // ---- phase 0: Mf 0-3 ----
    if (pf) stageA(h+3);
    bf16x8 af0[4], bfr[4];
    #pragma unroll
    for (int Mf=0;Mf<4;Mf++)
      af0[Mf] = *(const bf16x8*)(lb + (wr*128 + Mf*16 + lrow)*64 + rsw);
    #pragma unroll
    for (int Nf=0;Nf<4;Nf++)
      bfr[Nf] = *(const bf16x8*)(lb + 16384 + (wc*64 + Nf*16 + lrow)*64 + rsw);
    asm volatile("s_waitcnt lgkmcnt(0)" ::: "memory");
    __builtin_amdgcn_sched_barrier(0);
    __builtin_amdgcn_s_setprio(1);
    #pragma unroll
    for (int Mf=0;Mf<4;Mf++)
      #pragma unroll
      for (int Nf=0;Nf<4;Nf++)
        acc[Mf][Nf] = __builtin_amdgcn_mfma_f32_16x16x32_bf16(af0[Mf], bfr[Nf], acc[Mf][Nf], 0, 0, 0);
    __builtin_amdgcn_s_setprio(0);
    __builtin_amdgcn_s_barrier();

    // ---- phase 1: Mf 4-7 (B frags reused in regs) ----
    if (pf) stageB(h+3);
    bf16x8 af1[4];
    #pragma unroll
    for (int Mf=0;Mf<4;Mf++)
      af1[Mf] = *(const bf16x8*)(lb + (wr*128 + (Mf+4)*16 + lrow)*64 + rsw);
    asm volatile("s_waitcnt lgkmcnt(0)" ::: "memory");
    __builtin_amdgcn_sched_barrier(0);
    __builtin_amdgcn_s_setprio(1);
    #pragma unroll
    for (int Mf=0;Mf<4;Mf++)
      #pragma unroll
      for (int Nf=0;Nf<4;Nf++)
        acc[Mf+4][Nf] = __builtin_amdgcn_mfma_f32_16x16x32_bf16(af1[Mf], bfr[Nf], acc[Mf+4][Nf], 0, 0, 0);
    __builtin_amdgcn_s_setprio(0);
    __builtin_amdgcn_s_barrier();
  }

  // epilogue: C/D layout col = lane&15, row = (lane>>4)*4 + reg
  #pragma unroll
  for (int Mf=0;Mf<8;Mf++){
    #pragma unroll
    for (int Nf=0;Nf<4;Nf++){
      #pragma unroll
      for (int rg=0;rg<4;rg++){
        int gm = m0 + wr*128 + Mf*16 + lq*4 + rg;
        int gn = n0 + wc*64 + Nf*16 + lrow;
        float v = acc[Mf][Nf][rg];
        if (MODE==0){
          v = fmaxf(v, 0.f) * rw[gm*E_NUM + z];
          outInter[(size_t)gm*(E_NUM*I_DIM) + (size_t)z*I_DIM + gn] = f2bf(v);
        } else {
          atomicAdd(&outAdd[(size_t)gm*H_DIM + gn], v);
        }
      }
    }
  }
}

extern "C" void kernel_launch(void* const* d_in, const int* in_sizes, int n_in,
                              void* d_out, int out_size, void* d_ws, size_t ws_size,
                              hipStream_t stream)
{
  const float* x   = (const float*)d_in[0];
  const float* rww = (const float*)d_in[1];
  const float* rwb = (const float*)d_in[2];
  const float* w1  = (const float*)d_in[3];  // (E, H, I)
  const float* w2  = (const float*)d_in[4];  // (E, I, H)
  float* out = (float*)d_out;

  char* ws = (char*)d_ws;
  float*          rwout = (float*)(ws);                         // 32 KB
  unsigned short* xb    = (unsigned short*)(ws + (1u<<16));     // 2 MB  @64KB
  unsigned short* inter = (unsigned short*)(ws + (4ull<<20));   // 64 MB @4MB
  unsigned short* wt    = (unsigned short*)(ws + (68ull<<20));  // 64 MB @68MB
  const size_t needed = 132ull<<20;

  zero_kernel<<<2048, 256, 0, stream>>>((float4*)out, out_size/4);
  if (ws_size < needed) return;

  void* k0 = (void*)gemm4b<0>;
  void* k1 = (void*)gemm4b<1>;
  hipFuncSetAttribute(k0, hipFuncAttributeMaxDynamicSharedMemorySize, 131072);
  hipFuncSetAttribute(k1, hipFuncAttributeMaxDynamicSharedMemorySize, 131072);

  router_kernel<<<CAP, 256, 0, stream>>>(x, rww, rwb, xb, rwout);

  dim3 tb(32,8);
  // W1 (E,H,I) -> W1^T per expert (I x H) bf16
  transpose_cvt<<<dim3(I_DIM/32, H_DIM/32, E_NUM), tb, 0, stream>>>(
      w1, wt, H_DIM, I_DIM, (long)H_DIM*I_DIM, (long)I_DIM*H_DIM);

  // GEMM1: inter[c, e*I+n] = bf16( relu( xb @ W1_e^T ) * rw[c,e] )
  // grid 512 = (4 mtiles x 16 ntiles) x 8 experts; K=1024 -> NH=32
  gemm4b<0><<<512, 512, 131072, stream>>>(
      xb, H_DIM, 0L,
      wt, H_DIM, (long)I_DIM*H_DIM,
      32, 64, rwout, inter, nullptr);

  // W2 flat (E*I x H) -> W2^T (H x E*I) bf16
  transpose_cvt<<<dim3(H_DIM/32, (E_NUM*I_DIM)/32, 1), tb, 0, stream>>>(
      w2, wt, E_NUM*I_DIM, H_DIM, 0L, 0L);

  // GEMM2: out[c,h] += inter[c,:] @ W2^T[h,:]; split-K z=16 slices of 2048 -> NH=64
  // grid 256 = (4 mtiles x 4 ntiles) x 16 z
  gemm4b<1><<<256, 512, 131072, stream>>>(
      inter, E_NUM*I_DIM, 2048L,
      wt,    E_NUM*I_DIM, 2048L,
      64, 16, nullptr, nullptr, out);
}